// Round 2
// baseline (429.458 us; speedup 1.0000x reference)
//
#include <hip/hip_runtime.h>
#include <stdint.h>

typedef __attribute__((ext_vector_type(8))) short short8;
typedef __attribute__((ext_vector_type(4))) float f32x4;

#define MFMA16 __builtin_amdgcn_mfma_f32_16x16x32_bf16

static constexpr int kNodes = 262144;
static constexpr int kOutD  = 320;

static constexpr int THREADS = 512;   // 8 waves
static constexpr int NBLOCKS = 256;
static constexpr int WTILES  = kNodes / 16;              // 16384 wave-tiles of 16 nodes
static constexpr int NWAVES  = NBLOCKS * (THREADS / 64); // 2048
static constexpr int ITERS   = WTILES / NWAVES;          // 8

// ---- LDS byte offsets ----
static constexpr int W1S  = 0;       // [192][256B]  W1_s^T  (row h, col k), swizzled
static constexpr int W2S  = 49152;   // [128][256B]  W2_s^T  (row o, col h), swizzled
static constexpr int W1V  = 81920;   // [64][128B]   W1_v^T  (row j, col i), swizzled
static constexpr int W2V  = 90112;   // [64][128B]   W2_v^T  (row j2, col j), swizzled
static constexpr int B1O  = 98304;   // 192 f32
static constexpr int B2O  = 99072;   // 128 f32
static constexpr int BUF0 = 99584;   // 8 waves x 6144B private scratch
static constexpr int SMEM_BYTES = BUF0 + 8 * 6144;   // 148736

__device__ __forceinline__ uint16_t f2bf(float f) {
  uint32_t u = __builtin_bit_cast(uint32_t, f);
  u += 0x7FFFu + ((u >> 16) & 1u);          // round-to-nearest-even
  return (uint16_t)(u >> 16);
}
__device__ __forceinline__ float bf2f(uint16_t u) {
  return __builtin_bit_cast(float, ((uint32_t)u) << 16);
}
__device__ __forceinline__ short8 pack8(const float4& a, const float4& b) {
  short8 r;
  r[0] = (short)f2bf(a.x); r[1] = (short)f2bf(a.y);
  r[2] = (short)f2bf(a.z); r[3] = (short)f2bf(a.w);
  r[4] = (short)f2bf(b.x); r[5] = (short)f2bf(b.y);
  r[6] = (short)f2bf(b.z); r[7] = (short)f2bf(b.w);
  return r;
}

extern "C" __global__ __launch_bounds__(THREADS, 2)
void fused_gate_mlp(const float* __restrict__ x_s, const float* __restrict__ x_v,
                    const float* __restrict__ W1_s, const float* __restrict__ b1_s,
                    const float* __restrict__ W1_v, const float* __restrict__ W2_s,
                    const float* __restrict__ b2_s, const float* __restrict__ W2_v,
                    float* __restrict__ out)
{
  extern __shared__ char smem[];
  const int tid = threadIdx.x;

  // ---------- stage weights once per block (only barrier below) ----------
  for (int idx = tid; idx < 128 * 192; idx += THREADS) {       // W1_s [k][h] -> [h][k]
    int k = idx / 192, h = idx - k * 192;
    *(uint16_t*)(smem + W1S + h * 256 + ((2 * k) ^ ((h & 7) << 4))) = f2bf(W1_s[idx]);
  }
  for (int idx = tid; idx < 128 * 128; idx += THREADS) {       // W2_s [h][o] -> [o][h]
    int k = idx >> 7, o = idx & 127;
    *(uint16_t*)(smem + W2S + o * 256 + ((2 * k) ^ ((o & 7) << 4))) = f2bf(W2_s[idx]);
  }
  for (int idx = tid; idx < 64 * 64; idx += THREADS) {         // W1_v/W2_v [i][j] -> [j][i]
    int i = idx >> 6, j = idx & 63;
    int off = j * 128 + ((2 * i) ^ ((j & 7) << 4));
    *(uint16_t*)(smem + W1V + off) = f2bf(W1_v[idx]);
    *(uint16_t*)(smem + W2V + off) = f2bf(W2_v[idx]);
  }
  if (tid < 192) ((float*)(smem + B1O))[tid] = b1_s[tid];
  if (tid < 128) ((float*)(smem + B2O))[tid] = b2_s[tid];
  __syncthreads();

  const int w  = tid >> 6;
  const int l  = tid & 63;
  const int lw = l & 15;
  const int lg = l >> 4;
  const int sx = (lw & 7) << 4;
  char* buf = smem + BUF0 + w * 6144;        // wave-private scratch
  const float* b1 = (const float*)(smem + B1O);
  const float* b2 = (const float*)(smem + B2O);

  const float inv_s = 0.08838834764831845f;  // 1/sqrt(128)
  const float inv_v = 0.125f;                // 1/sqrt(64)

  int wt = blockIdx.x * 8 + w;               // wave-tile id (16 nodes each)

  // ---------- register prefetch of iteration 0 ----------
  float4 pfs[8], pfv[12];
  {
    const float4* ps = (const float4*)(x_s + (size_t)wt * 2048);
    const float4* pv = (const float4*)(x_v + (size_t)wt * 3072);
#pragma unroll
    for (int kt = 0; kt < 4; ++kt) {         // A-fragment addressing: row lw, k=kt*32+lg*8
      pfs[2 * kt + 0] = ps[lw * 32 + kt * 8 + lg * 2 + 0];
      pfs[2 * kt + 1] = ps[lw * 32 + kt * 8 + lg * 2 + 1];
    }
#pragma unroll
    for (int p = 0; p < 12; ++p) pfv[p] = pv[l + p * 64];
  }

  for (int t = 0; t < ITERS; ++t) {
    const int node0 = wt * 16;

    // ---------- stage x_v tile into buf ([rr=3n+c][i] bf16, swizzled) ----------
#pragma unroll
    for (int p = 0; p < 12; ++p) {
      unsigned idx4 = (unsigned)l + p * 64;
      unsigned n = idx4 / 48, rem = idx4 - n * 48;
      float v[4] = {pfv[p].x, pfv[p].y, pfv[p].z, pfv[p].w};
#pragma unroll
      for (int e = 0; e < 4; ++e) {
        unsigned fe = rem * 4 + e, i = fe / 3, c = fe - i * 3, rr = n * 3 + c;
        *(uint16_t*)(buf + rr * 128 + ((2 * i) ^ ((rr & 7) << 4))) = f2bf(v[e]);
      }
    }

    // ---------- x_s A-fragments straight from registers ----------
    short8 axs[4];
#pragma unroll
    for (int kt = 0; kt < 4; ++kt) axs[kt] = pack8(pfs[2 * kt], pfs[2 * kt + 1]);

    // ---------- prefetch next iteration (wraps; always in-bounds) ----------
    const int nwt = (wt + NWAVES) & (WTILES - 1);
    {
      const float4* ps = (const float4*)(x_s + (size_t)nwt * 2048);
      const float4* pv = (const float4*)(x_v + (size_t)nwt * 3072);
#pragma unroll
      for (int kt = 0; kt < 4; ++kt) {
        pfs[2 * kt + 0] = ps[lw * 32 + kt * 8 + lg * 2 + 0];
        pfs[2 * kt + 1] = ps[lw * 32 + kt * 8 + lg * 2 + 1];
      }
#pragma unroll
      for (int p = 0; p < 12; ++p) pfv[p] = pv[l + p * 64];
    }

    // ---------- x_v A-fragments ----------
    short8 axv[3][2];
#pragma unroll
    for (int m2 = 0; m2 < 3; ++m2)
#pragma unroll
      for (int kt = 0; kt < 2; ++kt)
        axv[m2][kt] = *(const short8*)(buf + (m2 * 16 + lw) * 128 + ((kt * 64 + lg * 16) ^ sx));

    // ---------- s1 = x_s @ W1_s ----------
    f32x4 accs[12];
#pragma unroll
    for (int i = 0; i < 12; ++i) accs[i] = (f32x4){0.f, 0.f, 0.f, 0.f};
#pragma unroll
    for (int kt = 0; kt < 4; ++kt) {
      const int kb = (kt * 64 + lg * 16) ^ sx;
#pragma unroll
      for (int ht = 0; ht < 12; ++ht) {
        short8 b = *(const short8*)(smem + W1S + (ht * 16 + lw) * 256 + kb);
        accs[ht] = MFMA16(axs[kt], b, accs[ht], 0, 0, 0);
      }
    }

    // ---------- v1 = x_v . W1_v ----------
    f32x4 accv[12];
#pragma unroll
    for (int i = 0; i < 12; ++i) accv[i] = (f32x4){0.f, 0.f, 0.f, 0.f};
#pragma unroll
    for (int kt = 0; kt < 2; ++kt) {
      const int kb = (kt * 64 + lg * 16) ^ sx;
#pragma unroll
      for (int jt = 0; jt < 4; ++jt) {
        short8 b = *(const short8*)(smem + W1V + (jt * 16 + lw) * 128 + kb);
#pragma unroll
        for (int m2 = 0; m2 < 3; ++m2)
          accv[m2 * 4 + jt] = MFMA16(axv[m2][kt], b, accv[m2 * 4 + jt], 0, 0, 0);
      }
    }

    // ---------- activation: scal -> buf[0..4K), gates -> buf[4K..6K) ----------
#pragma unroll
    for (int ht = 0; ht < 12; ++ht) {
      const int h = ht * 16 + lw;
      const float bb = b1[h];
#pragma unroll
      for (int r = 0; r < 4; ++r) {
        const int n = lg * 4 + r;
        float v = accs[ht][r] * inv_s + bb;
        float sg = 1.0f / (1.0f + __expf(-v));
        if (ht < 8)
          *(uint16_t*)(buf + n * 256 + ((2 * h) ^ ((n & 7) << 4))) = f2bf(v * sg);
        else
          *(uint16_t*)(buf + 4096 + n * 128 + 2 * ((ht - 8) * 16 + lw)) = f2bf(sg);
      }
    }

    // ---------- read scal A-fragments + all gates into registers ----------
    short8 as2[4];
#pragma unroll
    for (int kt = 0; kt < 4; ++kt)
      as2[kt] = *(const short8*)(buf + lw * 256 + ((kt * 64 + lg * 16) ^ sx));

    float gv[3][4][4];
#pragma unroll
    for (int m2 = 0; m2 < 3; ++m2)
#pragma unroll
      for (int r = 0; r < 4; ++r) {
        const unsigned rr = m2 * 16 + lg * 4 + r;
        const unsigned n = rr / 3;
#pragma unroll
        for (int jt = 0; jt < 4; ++jt)
          gv[m2][r][jt] = bf2f(*(const uint16_t*)(buf + 4096 + n * 128 + 2 * (jt * 16 + lw)));
      }

    // ---------- v_g -> buf (clobbers scal+gates; all reads are in regs) ----------
#pragma unroll
    for (int m2 = 0; m2 < 3; ++m2)
#pragma unroll
      for (int r = 0; r < 4; ++r) {
        const unsigned rr = m2 * 16 + lg * 4 + r;
#pragma unroll
        for (int jt = 0; jt < 4; ++jt) {
          const int j = jt * 16 + lw;
          float vgv = accv[m2 * 4 + jt][r] * inv_v * gv[m2][r][jt];
          *(uint16_t*)(buf + rr * 128 + ((2 * j) ^ ((rr & 7) << 4))) = f2bf(vgv);
        }
      }

    // ---------- out_s = scal @ W2_s ----------
    f32x4 acco[8];
#pragma unroll
    for (int i = 0; i < 8; ++i) acco[i] = (f32x4){0.f, 0.f, 0.f, 0.f};
#pragma unroll
    for (int kt = 0; kt < 4; ++kt) {
      const int kb = (kt * 64 + lg * 16) ^ sx;
#pragma unroll
      for (int ot = 0; ot < 8; ++ot) {
        short8 b = *(const short8*)(smem + W2S + (ot * 16 + lw) * 256 + kb);
        acco[ot] = MFMA16(as2[kt], b, acco[ot], 0, 0, 0);
      }
    }

    // ---------- v_g A-fragments ----------
    short8 avg_[3][2];
#pragma unroll
    for (int m2 = 0; m2 < 3; ++m2)
#pragma unroll
      for (int kt = 0; kt < 2; ++kt)
        avg_[m2][kt] = *(const short8*)(buf + (m2 * 16 + lw) * 128 + ((kt * 64 + lg * 16) ^ sx));

    // ---------- out_v = v_g . W2_v ----------
    f32x4 accw[12];
#pragma unroll
    for (int i = 0; i < 12; ++i) accw[i] = (f32x4){0.f, 0.f, 0.f, 0.f};
#pragma unroll
    for (int kt = 0; kt < 2; ++kt) {
      const int kb = (kt * 64 + lg * 16) ^ sx;
#pragma unroll
      for (int jt = 0; jt < 4; ++jt) {
        short8 b = *(const short8*)(smem + W2V + (jt * 16 + lw) * 128 + kb);
#pragma unroll
        for (int m2 = 0; m2 < 3; ++m2)
          accw[m2 * 4 + jt] = MFMA16(avg_[m2][kt], b, accw[m2 * 4 + jt], 0, 0, 0);
      }
    }

    // ---------- epilogue ----------
    float* orow = out + (size_t)node0 * kOutD;
#pragma unroll
    for (int ot = 0; ot < 8; ++ot) {
      const int o = ot * 16 + lw;
      const float bb = b2[o];
#pragma unroll
      for (int r = 0; r < 4; ++r)
        orow[(size_t)(lg * 4 + r) * kOutD + o] = acco[ot][r] * inv_s + bb;
    }
#pragma unroll
    for (int m2 = 0; m2 < 3; ++m2)
#pragma unroll
      for (int r = 0; r < 4; ++r) {
        const unsigned rr = m2 * 16 + lg * 4 + r;
        const unsigned n = rr / 3, c = rr - 3 * n;
#pragma unroll
        for (int jt = 0; jt < 4; ++jt)
          orow[(size_t)n * kOutD + 128 + (jt * 16 + lw) * 3 + c] = accw[m2 * 4 + jt][r] * inv_v;
      }

    wt = nwt;
  }
}

extern "C" void kernel_launch(void* const* d_in, const int* in_sizes, int n_in,
                              void* d_out, int out_size, void* d_ws, size_t ws_size,
                              hipStream_t stream) {
  const float* x_s  = (const float*)d_in[0];
  const float* x_v  = (const float*)d_in[1];
  const float* W1_s = (const float*)d_in[2];
  const float* b1_s = (const float*)d_in[3];
  const float* W1_v = (const float*)d_in[4];
  const float* W2_s = (const float*)d_in[5];
  const float* b2_s = (const float*)d_in[6];
  const float* W2_v = (const float*)d_in[7];
  float* o = (float*)d_out;
  hipLaunchKernelGGL(fused_gate_mlp, dim3(NBLOCKS), dim3(THREADS), SMEM_BYTES, stream,
                     x_s, x_v, W1_s, b1_s, W1_v, W2_s, b2_s, W2_v, o);
}